// Round 9
// baseline (249.057 us; speedup 1.0000x reference)
//
#include <hip/hip_runtime.h>

#define PLANE 65536
#define WIDTH 256
#define PADW 258
#define PADPLANE 66564   // 258*258

typedef __bf16 v8bf __attribute__((ext_vector_type(8)));
typedef float  v4f  __attribute__((ext_vector_type(4)));

typedef const __attribute__((address_space(1))) unsigned int* gas_ptr;
typedef __attribute__((address_space(3))) unsigned int* las_ptr;

// async global->LDS, 16 B per lane; LDS dest = wave-uniform base (+HW lane*16)
__device__ __forceinline__ void gl_lds(const void* g, void* l) {
  __builtin_amdgcn_global_load_lds((gas_ptr)g, (las_ptr)l, 16, 0, 0);
}

// self-inverse 16B-chunk swizzle within 8-chunk groups; 0 conflicts measured
// (rounds 6-8 PMC).
__device__ __forceinline__ int swz(int c) {
  return (c & ~7) | ((c & 7) ^ ((c >> 3) & 7));
}

__device__ __forceinline__ unsigned int pack2(float a, float b) {
  __bf16 ba = (__bf16)a, bb = (__bf16)b;
  unsigned short sa = __builtin_bit_cast(unsigned short, ba);
  unsigned short sb = __builtin_bit_cast(unsigned short, bb);
  return (unsigned int)sa | ((unsigned int)sb << 16);
}

// ---------------------------------------------------------------------------
// prep: V, C_new, H (Laplacian), and stage vs = V/sf (fp32, unpadded NCHW).
// ---------------------------------------------------------------------------
__global__ __launch_bounds__(256) void prep_k(
    const float* __restrict__ inputs, const float* __restrict__ H0,
    const float* __restrict__ C0, const float* __restrict__ c2p,
    const float* __restrict__ sfp, float* __restrict__ dout,
    float* __restrict__ vs)
{
  int p = blockIdx.x * 256 + threadIdx.x;      // 0 .. 524287
  int b = p >> 16;
  int i = p & 65535;
  int y = i >> 8;
  int x = i & 255;
  float in   = inputs[p];
  float h0   = H0[p];
  float c0a  = C0[b * 131072 + i];             // C0[:,0]
  float up    = (y > 0)   ? inputs[p - 256] : 0.f;
  float down  = (y < 255) ? inputs[p + 256] : 0.f;
  float left  = (x > 0)   ? inputs[p - 1]   : 0.f;
  float right = (x < 255) ? inputs[p + 1]   : 0.f;
  float lap = up + down + left + right - 4.f * in;
  float c2 = c2p[0];
  float sf = sfp[0];
  float Hv = 2.f * in - c0a + c2 * lap;
  float V  = in - h0;
  dout[524288 + p]  = Hv;                      // H
  dout[2097152 + p] = V;                       // V
  dout[1048576 + b * 131072 + i]         = in;   // C_new[:,0]
  dout[1048576 + b * 131072 + 65536 + i] = c0a;  // C_new[:,1]
  vs[p] = V / sf;                              // conv-chain input
}

// ---------------------------------------------------------------------------
// weight prep: w1t[tap][cout] fp32; B2t[cout][tap*32+cin] bf16;
//              B3t[cout][tap*64+cin] bf16; w4t[tap][cin] fp32.
// ---------------------------------------------------------------------------
__global__ __launch_bounds__(256) void wtrans_k(
    const float* __restrict__ w1, const float* __restrict__ w2,
    const float* __restrict__ w3, const float* __restrict__ w4,
    float* __restrict__ w1t, __bf16* __restrict__ B2t,
    __bf16* __restrict__ B3t, float* __restrict__ w4t)
{
  int t = blockIdx.x * 256 + threadIdx.x;
  if (t < 288) {                       // w1: [32][1][9] -> [tap][32]
    int tap = t >> 5, cout = t & 31;
    w1t[t] = w1[cout * 9 + tap];
  }
  int t2 = t - 288;
  if (t2 >= 0 && t2 < 18432) {         // 64 x 288
    int cout = t2 / 288, k = t2 % 288;
    int tap = k / 32, cin = k % 32;
    B2t[t2] = (__bf16)w2[cout * 288 + cin * 9 + tap];
  }
  int t3 = t - (288 + 18432);
  if (t3 >= 0 && t3 < 18432) {         // 32 x 576
    int cout = t3 / 576, k = t3 % 576;
    int tap = k / 64, cin = k % 64;
    B3t[t3] = (__bf16)w3[cout * 576 + cin * 9 + tap];
  }
  int t4 = t - (288 + 18432 + 18432);
  if (t4 >= 0 && t4 < 288) {           // w4: [1][32][9] -> [tap][32]
    int tap = t4 >> 5, cin = t4 & 31;
    w4t[t4] = w4[cin * 9 + tap];
  }
}

// ---------------------------------------------------------------------------
// zero the 1-px padding ring of act1/act3 only (act2 now lives in LDS).
// ---------------------------------------------------------------------------
#define R1 (8 * 1028 * 16)
#define R3 (8 * 1028 * 16)
__global__ __launch_bounds__(256) void zero_k(
    __bf16* __restrict__ a1, __bf16* __restrict__ a3)
{
  int t = blockIdx.x * 256 + threadIdx.x;
  unsigned int* p; int idx;
  if (t < R1)            { p = (unsigned int*)a1; idx = t; }
  else if (t < R1 + R3)  { p = (unsigned int*)a3; idx = t - R1; }
  else return;
  int ch = idx & 15;
  int pr = idx >> 4;                 // 0 .. 8*1028-1
  int b = pr / 1028, r = pr % 1028;
  int y, x;
  if      (r < 258) { y = 0;           x = r; }
  else if (r < 516) { y = 257;         x = r - 258; }
  else if (r < 772) { y = r - 516 + 1; x = 0; }
  else              { y = r - 772 + 1; x = 257; }
  p[((size_t)b * PADPLANE + y * PADW + x) * 16 + ch] = 0;
}

// ---------------------------------------------------------------------------
// conv1: 1->32 fp32 vector, thread/pixel; writes act1 NHWC bf16 padded.
// ---------------------------------------------------------------------------
__global__ __launch_bounds__(256) void conv1_k(
    const float* __restrict__ vs, const float* __restrict__ w1t,
    const float* __restrict__ b1, __bf16* __restrict__ act1)
{
  int x = threadIdx.x, y = blockIdx.x, b = blockIdx.y;
  const float* ip = vs + ((size_t)b << 16) + y * WIDTH + x;
  float acc[32];
  #pragma unroll
  for (int i = 0; i < 32; i++) acc[i] = b1[i];
  #pragma unroll
  for (int tap = 0; tap < 9; tap++) {
    int dy = tap / 3 - 1, dx = tap % 3 - 1;
    int yy = y + dy, xx = x + dx;
    bool ok = (yy >= 0 && yy < 256 && xx >= 0 && xx < 256);
    float v = ok ? ip[dy * WIDTH + dx] : 0.f;
    const float* wp = w1t + tap * 32;           // uniform
    #pragma unroll
    for (int i = 0; i < 32; i++) acc[i] = fmaf(wp[i], v, acc[i]);
  }
  unsigned int u[16];
  #pragma unroll
  for (int j = 0; j < 16; j++)
    u[j] = pack2(fmaxf(acc[2*j], 0.f), fmaxf(acc[2*j+1], 0.f));
  size_t pa = ((size_t)b * PADPLANE + (y+1) * PADW + (x+1)) * 32;
  uint4* op = reinterpret_cast<uint4*>(act1 + pa);
  #pragma unroll
  for (int j = 0; j < 4; j++)
    op[j] = make_uint4(u[4*j], u[4*j+1], u[4*j+2], u[4*j+3]);
}

// ---------------------------------------------------------------------------
// conv23 fused (32->64->32): act2 NEVER touches HBM — it lives in an LDS
// ring of 3 rows. Block = 4 waves, x-tile 64 (act2 window 66 px, act1
// window 68 px), y-slab 32 rows. Per iter: async-stage 1 act1 row (ring-4),
// conv2 -> act2 LDS row, barrier, conv3 -> act3 HBM row, barrier.
// conv2 M-tiles (5 of 16): waves {0,4},{1},{2},{3}; all 64 couts' B in regs.
// conv3 M-tiles (4): one/wave; all 32 couts' B in regs.
// Edge rows (-1/256) and edge cols (x=-1/256 equivalents) zero-filled in LDS.
// ---------------------------------------------------------------------------
#define A1SLOT 5376    // 84 px * 64 B  (reads reach w<=82)
#define A2SLOT 10496   // 82 px * 128 B (stores reach p<=80)
#define SLAB23 32

__global__ __launch_bounds__(256, 1) void conv23_k(
    const __bf16* __restrict__ act1, const __bf16* __restrict__ B2t,
    const __bf16* __restrict__ B3t, const float* __restrict__ b2,
    const float* __restrict__ b3, __bf16* __restrict__ act3)
{
  __shared__ __align__(16) char sm1[4 * A1SLOT];
  __shared__ __align__(16) char sm2[3 * A2SLOT];

  const int lane = threadIdx.x & 63, wave = threadIdx.x >> 6;
  const int l15 = lane & 15, q = lane >> 4;
  const int y0 = blockIdx.x * SLAB23;
  const int x0 = blockIdx.y * 64;
  const int b  = blockIdx.z;
  // act2 window px p <-> unpadded col x0-1+p; act1 window w <-> col x0-2+w.
  const int s2 = (x0 == 0) ? 1 : 0;                      // first computed p
  const int z2 = (x0 == 0) ? 0 : ((x0 == 192) ? 65 : -1);// zero-pad column
  const int gcol0 = x0 - 1;          // padded col of act1-window w=0 (may be -1)
  const int nmt = (wave == 0) ? 2 : 1;

  const char* plane1 = (const char*)(act1 + (size_t)b * PADPLANE * 32);

  // ---- B-fragment + bias hoists (one-time) ----
  v8bf b2r[9][4];
  float bv2[4];
  #pragma unroll
  for (int tap = 0; tap < 9; tap++)
    #pragma unroll
    for (int nt = 0; nt < 4; nt++)
      b2r[tap][nt] = *(const v8bf*)(B2t + (size_t)(nt * 16 + l15) * 288
                                        + tap * 32 + q * 8);
  #pragma unroll
  for (int nt = 0; nt < 4; nt++) bv2[nt] = b2[nt * 16 + l15];

  v8bf b3r[9][2][2];
  float bv3[2];
  #pragma unroll
  for (int tap = 0; tap < 9; tap++)
    #pragma unroll
    for (int kb = 0; kb < 2; kb++)
      #pragma unroll
      for (int nt = 0; nt < 2; nt++)
        b3r[tap][kb][nt] = *(const v8bf*)(B3t + (size_t)(nt * 16 + l15) * 576
                                              + tap * 64 + kb * 32 + q * 8);
  bv3[0] = b3[l15]; bv3[1] = b3[16 + l15];

  // ---- stage one act1 row (68 px = 272 chunks; 68/wave) ----
  auto stage1 = [&](int rr) {              // unpadded act1 row in [-1,256]
    if (rr < -1 || rr > 256) return;
    char* lrow = sm1 + (size_t)((rr + 4) & 3) * A1SLOT;
    const char* g = plane1 + (long)((rr + 1) * PADW + gcol0) * 64;
    const int base = wave * 68;
    {
      int c = base + lane;
      gl_lds(g + (long)swz(c) * 16, lrow + (size_t)base * 16);
    }
    if (lane < 4) {
      int c = base + 64 + lane;
      gl_lds(g + (long)swz(c) * 16, lrow + (size_t)(base + 64) * 16);
    }
  };

  // ---- conv2: one act2 row into LDS ring ----
  auto conv2row = [&](int n2) {            // act2 row in [-1,256]
    char* wr = sm2 + (size_t)(((n2 % 3) + 3) % 3) * A2SLOT;
    if (n2 < 0 || n2 > 255) {              // zero-pad row
      for (int c = threadIdx.x; c < 528; c += 256)
        *(uint4*)(wr + (size_t)c * 16) = make_uint4(0, 0, 0, 0);
      return;
    }
    const char* a1p[3];
    #pragma unroll
    for (int dy = 0; dy < 3; dy++)
      a1p[dy] = sm1 + (size_t)((n2 - 1 + dy + 4) & 3) * A1SLOT;
    v4f acc[2][4];
    #pragma unroll
    for (int mi = 0; mi < 2; mi++)
      #pragma unroll
      for (int nt = 0; nt < 4; nt++)
        acc[mi][nt] = (v4f){bv2[nt], bv2[nt], bv2[nt], bv2[nt]};
    #pragma unroll
    for (int tap = 0; tap < 9; tap++) {
      const int dy = tap / 3, dx = tap % 3;
      v8bf af[2];
      #pragma unroll
      for (int mi = 0; mi < 2; mi++) if (mi < nmt) {
        int tile = (mi == 0) ? wave : 4;
        int w = s2 + tile * 16 + l15 + dx;           // act1 window coord
        af[mi] = *(const v8bf*)(a1p[dy] + (size_t)swz(w * 4 + q) * 16);
      }
      #pragma unroll
      for (int mi = 0; mi < 2; mi++) if (mi < nmt)
        #pragma unroll
        for (int nt = 0; nt < 4; nt++)
          acc[mi][nt] = __builtin_amdgcn_mfma_f32_16x16x32_bf16(
              af[mi], b2r[tap][nt], acc[mi][nt], 0, 0, 0);
    }
    #pragma unroll
    for (int mi = 0; mi < 2; mi++) if (mi < nmt) {
      int tile = (mi == 0) ? wave : 4;
      #pragma unroll
      for (int r = 0; r < 4; r++) {
        int p = s2 + tile * 16 + q * 4 + r;
        #pragma unroll
        for (int nt = 0; nt < 4; nt++) {
          int c = p * 8 + nt * 2 + (l15 >> 3);
          *(__bf16*)(wr + (size_t)swz(c) * 16 + (l15 & 7) * 2) =
              (__bf16)fmaxf(acc[mi][nt][r], 0.f);
        }
      }
    }
    // zero-pad edge column (after tile stores; same-wave ordering: wave 0)
    if (z2 >= 0 && threadIdx.x < 8)
      *(uint4*)(wr + (size_t)swz(z2 * 8 + (int)threadIdx.x) * 16) =
          make_uint4(0, 0, 0, 0);
  };

  // ---- conv3: one act3 row from LDS act2 ring -> HBM ----
  auto conv3row = [&](int r3) {
    v4f acc[2];
    #pragma unroll
    for (int nt = 0; nt < 2; nt++)
      acc[nt] = (v4f){bv3[nt], bv3[nt], bv3[nt], bv3[nt]};
    #pragma unroll
    for (int t = 0; t < 3; t++) {
      const char* ar = sm2 + (size_t)((r3 - 1 + t + 3) % 3) * A2SLOT;
      #pragma unroll
      for (int dx = 0; dx < 3; dx++)
        #pragma unroll
        for (int kb = 0; kb < 2; kb++) {
          int j = wave * 16 + l15;
          v8bf af = *(const v8bf*)(ar
              + (size_t)swz((j + dx) * 8 + kb * 4 + q) * 16);
          #pragma unroll
          for (int nt = 0; nt < 2; nt++)
            acc[nt] = __builtin_amdgcn_mfma_f32_16x16x32_bf16(
                af, b3r[t * 3 + dx][kb][nt], acc[nt], 0, 0, 0);
        }
    }
    size_t rb = ((size_t)b * PADPLANE + (size_t)(r3 + 1) * PADW + x0 + 1) * 32;
    #pragma unroll
    for (int r = 0; r < 4; r++) {
      int j = wave * 16 + q * 4 + r;
      #pragma unroll
      for (int nt = 0; nt < 2; nt++)
        act3[rb + (size_t)j * 32 + nt * 16 + l15] =
            (__bf16)fmaxf(acc[nt][r], 0.f);
    }
  };

  // ---- prime ----
  stage1(y0 - 2); stage1(y0 - 1); stage1(y0); stage1(y0 + 1);
  __syncthreads();
  conv2row(y0 - 1);
  __syncthreads();
  stage1(y0 + 2);
  conv2row(y0);
  __syncthreads();

  // ---- steady loop: one output row / iter ----
  for (int i = 0; i < SLAB23; i++) {
    int r = y0 + i;
    stage1(r + 3);                         // overlaps conv2 below
    conv2row(r + 1);
    __syncthreads();                       // act2 row r+1 visible (+vm drain)
    conv3row(r);
    __syncthreads();                       // protect act2 slot r-1 & act1 ring
  }
}

// ---------------------------------------------------------------------------
// conv4 (32->1) row-streaming: thread = one x-column, block = 4 output rows.
// Fused epilogue: V_hat = (conv+b4)*sf ; outputs = H + V_hat.
// ---------------------------------------------------------------------------
#define C4ROWS 4
__global__ __launch_bounds__(256) void conv4_k(
    const __bf16* __restrict__ act3, const float* __restrict__ w4t,
    const float* __restrict__ b4, const float* __restrict__ sfp,
    float* __restrict__ dout)
{
  const int x = threadIdx.x, y0 = blockIdx.x * C4ROWS, b = blockIdx.y;
  const float b4v = b4[0], sf = sfp[0];
  const uint4* base = (const uint4*)(act3 + (size_t)b * PADPLANE * 32);
  float accs[3] = {b4v, b4v, b4v};

  #pragma unroll
  for (int t = 0; t < C4ROWS + 2; t++) {
    const int pr = y0 + t;                       // padded row index
    const uint4* rp = base + ((size_t)pr * PADW + x) * 4;   // 4 uint4 / px
    uint4 L[12];
    #pragma unroll
    for (int j = 0; j < 12; j++) L[j] = rp[j];
    #pragma unroll
    for (int j = 0; j < 12; j++) {
      const int dx = j >> 2, c0 = (j & 3) * 8;
      unsigned int uu[4] = {L[j].x, L[j].y, L[j].z, L[j].w};
      float f[8];
      #pragma unroll
      for (int k = 0; k < 4; k++) {
        f[2*k]   = __builtin_bit_cast(float, uu[k] << 16);
        f[2*k+1] = __builtin_bit_cast(float, uu[k] & 0xFFFF0000u);
      }
      #pragma unroll
      for (int dyp = 0; dyp < 3; dyp++) {
        if (dyp <= t && t - dyp < C4ROWS) {
          const int slot = (t - dyp) % 3;
          const float* wp = w4t + (dyp * 3 + dx) * 32 + c0;   // uniform
          #pragma unroll
          for (int k = 0; k < 8; k++)
            accs[slot] = fmaf(wp[k], f[k], accs[slot]);
        }
      }
    }
    if (t >= 2) {                                // output row y0+t-2 complete
      const int r = y0 + t - 2, slot = (t - 2) % 3;
      size_t p0 = ((size_t)b << 16) + (size_t)r * WIDTH + x;
      float vh = accs[slot] * sf;
      dout[p0]           = dout[524288 + p0] + vh;   // outputs = H + V_hat
      dout[2621440 + p0] = vh;                       // V_hat
      accs[slot] = b4v;
    }
  }
}

// ---------------------------------------------------------------------------
extern "C" void kernel_launch(void* const* d_in, const int* in_sizes, int n_in,
                              void* d_out, int out_size, void* d_ws, size_t ws_size,
                              hipStream_t stream) {
  const float* inputs = (const float*)d_in[0];
  const float* H0     = (const float*)d_in[1];
  const float* C0     = (const float*)d_in[2];
  const float* c2     = (const float*)d_in[3];
  const float* sf     = (const float*)d_in[4];
  const float* w1     = (const float*)d_in[5];
  const float* b1     = (const float*)d_in[6];
  const float* w2     = (const float*)d_in[7];
  const float* b2     = (const float*)d_in[8];
  const float* w3     = (const float*)d_in[9];
  const float* b3     = (const float*)d_in[10];
  const float* w4     = (const float*)d_in[11];
  const float* b4     = (const float*)d_in[12];
  float* out = (float*)d_out;
  float* ws  = (float*)d_ws;

  float*  vs   = ws;                               // 524288 fp32
  float*  w1t  = ws + 524288;                      // 288 fp32
  float*  w4t  = ws + 524576;                      // 288 fp32
  __bf16* B2t  = (__bf16*)(ws + 524864);           // 18432 bf16
  __bf16* B3t  = (__bf16*)(ws + 534080);           // 18432 bf16
  __bf16* act1 = (__bf16*)(ws + 543296);           // 8*66564*32 bf16
  // act2 region no longer used (act2 lives in LDS); act3 kept at old offset.
  __bf16* act3 = act1 + (size_t)8 * PADPLANE * 32
                      + (size_t)8 * PADPLANE * 64;

  prep_k<<<2048, 256, 0, stream>>>(inputs, H0, C0, c2, sf, out, vs);
  wtrans_k<<<147, 256, 0, stream>>>(w1, w2, w3, w4, w1t, B2t, B3t, w4t);
  zero_k<<<1028, 256, 0, stream>>>(act1, act3);
  conv1_k<<<dim3(256, 8), 256, 0, stream>>>(vs, w1t, b1, act1);
  conv23_k<<<dim3(8, 4, 8), 256, 0, stream>>>(act1, B2t, B3t, b2, b3, act3);
  conv4_k<<<dim3(64, 8), 256, 0, stream>>>(act3, w4t, b4, sf, out);
}